// Round 8
// baseline (374.240 us; speedup 1.0000x reference)
//
#include <hip/hip_runtime.h>
#include <hip/hip_bf16.h>
#include <hip/hip_fp16.h>

// Encoder: neigh_feats = mean(raw[idx], axis=1); x = nf @ W; BN(train); LeakyReLU(0.01)
// Inputs: raw[100000,128]f32, W[128,128]f32, gamma[128], beta[128], idx[50000,16]i32
// Output: [50000,128] f32
//
// R8 == R7 with the work-queue grab made BLOCK-UNIFORM (R7 bug: per-thread
// atomicAdd gave every lane a different tile -> cross-lane shfl of mismatched
// tiles + queues drained 256x too fast -> poisoned nf, absmax 44).
// XCD-locality design: raw partitioned by feature into 8 x 3.2MB f16 partitions;
// a block gathers only the partition of its own XCD (s_getreg XCC_ID) so the
// partition stays L2-resident (~200cyc vs ~700cyc). Per-partition atomic queues
// + stealing keep correctness independent of the XCD mapping.
//   enc_conv:     raw f32 -> rawp[8][100000][16]f16 (LDS transpose), Wt, zero state
//   enc_gather_p: XCD-local partition gather+mean -> nf[50000][128]f16
//   enc_mm:       MFMA f16 GEMM (R5-proven), x -> f16 ws + f32 stats
//   enc_bn_h:     BN+LeakyReLU, f16 x -> f32 out
// Harness floor ~80us (256MiB ws re-poison) is untouchable.

#define NTOTAL 100000
#define FEAT   128
#define NB     50000
#define KNEI   16
#define NTILES (NB / 16)   // 3125

// ws layout
#define OFF_STATS 0                          // 256 f32
#define OFF_QCNT  1024                       // 16 int
#define OFF_WT    2048                       // 128*128 f16 = 32KB
#define OFF_RAWP  34816                      // 8*100000*16 f16 = 25.6MB
#define OFF_NF    (34816 + 25600000)         // 50000*128 f16 = 12.8MB
#define OFF_XH    (34816 + 25600000 + 12800000)  // 50000*128 f16 = 12.8MB
#define WS_NEEDED (OFF_XH + 12800000)

typedef float f32x4 __attribute__((ext_vector_type(4)));
typedef short bf16x8 __attribute__((ext_vector_type(8)));
typedef _Float16 f16x8 __attribute__((ext_vector_type(8)));

__device__ __forceinline__ unsigned short f2bf(float f) {
    union { float f; unsigned u; } v; v.f = f;
    unsigned r = v.u + 0x7FFF + ((v.u >> 16) & 1);
    return (unsigned short)(r >> 16);
}
__device__ __forceinline__ unsigned h2add(unsigned a, unsigned b) {
    union { unsigned u; __half2 h; } x, y, r;
    x.u = a; y.u = b; r.h = __hadd2(x.h, y.h);
    return r.u;
}
__device__ __forceinline__ unsigned h2scale16(unsigned a) {   // * 0.0625 packed
    union { unsigned u; __half2 h; } x, c, r;
    x.u = a; c.u = 0x2C002C00u;
    r.h = __hmul2(x.h, c.h);
    return r.u;
}
__device__ __forceinline__ unsigned packh2(float a, float b) {
    union { unsigned u; __half2 h; } r;
    r.h = __float22half2_rn(make_float2(a, b));
    return r.u;
}

// ---- conv: raw -> rawp (feature-partitioned f16), W -> Wt f16^T, zero state ----
__global__ __launch_bounds__(256) void enc_conv(
    const float* __restrict__ raw, const float* __restrict__ W,
    unsigned short* __restrict__ rawp, unsigned short* __restrict__ Wt,
    float* __restrict__ gstats, int* __restrict__ qcnt)
{
    __shared__ unsigned sT[16][68];   // 16 nodes x 64 h2-pairs, pad 4
    const int t = threadIdx.x;
    if (blockIdx.x < 64) {            // Wt[n*128+k] = f16(W[k*128+n])
        int e = blockIdx.x * 256 + t;
        int n = e >> 7, k = e & 127;
        union { unsigned short s; __half h; } c; c.h = __float2half(W[k * FEAT + n]);
        Wt[e] = c.s;
    }
    if (blockIdx.x == 64 && t < 2 * FEAT) gstats[t] = 0.f;
    if (blockIdx.x == 65 && t < 16) qcnt[t] = 0;

    const float4* raw4 = (const float4*)raw;
    const int pp = t >> 5, nl = (t >> 1) & 15, hh = t & 1;   // write mapping
    for (int b = blockIdx.x; b < NTOTAL / 16; b += gridDim.x) {
        const int n0 = b * 16;
        __syncthreads();              // protect sT reuse
        #pragma unroll
        for (int i = 0; i < 2; ++i) {
            int e = t + i * 256;      // 0..511 float4 of this 16-node batch
            int n = e >> 5, c = e & 31;
            float4 v = raw4[(size_t)(n0 + n) * 32 + c];
            sT[n][c * 2]     = packh2(v.x, v.y);
            sT[n][c * 2 + 1] = packh2(v.z, v.w);
        }
        __syncthreads();
        // thread (p,nl,h) writes 16B: features p*16+h*8 .. +7 of node n0+nl
        uint4 o;
        o.x = sT[nl][pp * 8 + hh * 4 + 0];
        o.y = sT[nl][pp * 8 + hh * 4 + 1];
        o.z = sT[nl][pp * 8 + hh * 4 + 2];
        o.w = sT[nl][pp * 8 + hh * 4 + 3];
        *(uint4*)&rawp[((size_t)pp * NTOTAL + n0 + nl) * 16 + hh * 8] = o;
    }
}

// ---- gather: XCD-local partition gather+mean -> nf ----------------------------
__global__ __launch_bounds__(256) void enc_gather_p(
    const unsigned short* __restrict__ rawp, const int* __restrict__ idx,
    unsigned short* __restrict__ nf, int* __restrict__ qcnt)
{
    __shared__ int sBase;
    int xcc;
    __asm__ __volatile__("s_getreg_b32 %0, hwreg(HW_REG_XCC_ID)" : "=s"(xcc));
    xcc &= 7;   // block-uniform (all waves share the CU); any value is CORRECT,
                // locality only if it's the real XCD id

    const int t = threadIdx.x, lane = t & 63, wv = t >> 6;
    const int h = lane & 1, k0 = (lane >> 1) & 7, rl = lane >> 4;   // rl 0..3
    const int comp = k0 & 3;   // idx int4-component is fixed per thread

    for (int j = 0; j < 8; ++j) {
        const int p2 = (xcc + j) & 7;
        const unsigned short* rp = rawp + (size_t)p2 * NTOTAL * 16;
        while (true) {
            __syncthreads();                          // protect sBase reuse
            if (t == 0) sBase = atomicAdd(&qcnt[p2], 8);
            __syncthreads();
            const int base = sBase;                   // BLOCK-UNIFORM batch grab
            if (base >= NTILES) break;                // uniform exit
            int lim = base + 8; if (lim > NTILES) lim = NTILES;
            for (int tile = base; tile < lim; ++tile) {
                // wave's 64 indices (rows wv*4..wv*4+3): lanes 0..15 hold int4s
                int4 iva = ((const int4*)idx)[tile * 64 + wv * 16 + (lane & 15)];
                uint4 s = {0u, 0u, 0u, 0u};
                #pragma unroll
                for (int kk = 0; kk < 2; ++kk) {
                    const int k = k0 + kk * 8;
                    const int e = rl * 16 + k;     // int offset in wave's idx block
                    const int src = e >> 2;        // holder lane (0..15)
                    int c0 = __shfl(iva.x, src), c1 = __shfl(iva.y, src);
                    int c2 = __shfl(iva.z, src), c3 = __shfl(iva.w, src);
                    int ik = comp == 0 ? c0 : comp == 1 ? c1 : comp == 2 ? c2 : c3;
                    uint4 v = *(const uint4*)&rp[(size_t)ik * 16 + h * 8];
                    s.x = h2add(s.x, v.x); s.y = h2add(s.y, v.y);
                    s.z = h2add(s.z, v.z); s.w = h2add(s.w, v.w);
                }
                // reduce over k0 (lane bits 1..3)
                #pragma unroll
                for (int d = 2; d <= 8; d <<= 1) {
                    s.x = h2add(s.x, __shfl_xor(s.x, d));
                    s.y = h2add(s.y, __shfl_xor(s.y, d));
                    s.z = h2add(s.z, __shfl_xor(s.z, d));
                    s.w = h2add(s.w, __shfl_xor(s.w, d));
                }
                if (k0 == 0) {
                    uint4 o;
                    o.x = h2scale16(s.x); o.y = h2scale16(s.y);
                    o.z = h2scale16(s.z); o.w = h2scale16(s.w);
                    const int row = tile * 16 + wv * 4 + rl;
                    *(uint4*)&nf[(size_t)row * FEAT + p2 * 16 + h * 8] = o;
                }
            }
        }
    }
}

// ---- mm: x = nf @ W via MFMA f16 (R5-proven structure); x -> f16 ws + stats ----
__global__ __launch_bounds__(256, 4) void enc_mm(
    const unsigned short* __restrict__ nf, const unsigned short* __restrict__ Wt,
    unsigned short* __restrict__ xh, float* __restrict__ gstats)
{
    const int t = threadIdx.x;
    const int lane = t & 63;
    const int wv = t >> 6;
    const int ln = lane & 15, qd = lane >> 4;
    const int n0 = wv * 32 + ln, n1 = n0 + 16;

    f16x8 b0[4], b1[4];
    #pragma unroll
    for (int kt = 0; kt < 4; ++kt) {
        const int k0 = kt * 32 + qd * 8;
        b0[kt] = *(const f16x8*)&Wt[n0 * FEAT + k0];
        b1[kt] = *(const f16x8*)&Wt[n1 * FEAT + k0];
    }

    float s1a = 0.f, s2a = 0.f, s1b = 0.f, s2b = 0.f;

    for (int tile = blockIdx.x; tile < NTILES; tile += gridDim.x) {
        const int i0 = tile * 16;
        f32x4 acc0 = {0.f, 0.f, 0.f, 0.f}, acc1 = {0.f, 0.f, 0.f, 0.f};
        #pragma unroll
        for (int kt = 0; kt < 4; ++kt) {
            const int k0 = kt * 32 + qd * 8;
            f16x8 a = *(const f16x8*)&nf[(size_t)(i0 + ln) * FEAT + k0];
            acc0 = __builtin_amdgcn_mfma_f32_16x16x32_f16(a, b0[kt], acc0, 0, 0, 0);
            acc1 = __builtin_amdgcn_mfma_f32_16x16x32_f16(a, b1[kt], acc1, 0, 0, 0);
        }
        #pragma unroll
        for (int ri = 0; ri < 4; ++ri) {
            const int row = i0 + qd * 4 + ri;
            float v0 = acc0[ri], v1 = acc1[ri];
            union { unsigned short s; __half h; } q0, q1;
            q0.h = __float2half(v0); q1.h = __float2half(v1);
            xh[row * FEAT + n0] = q0.s;
            xh[row * FEAT + n1] = q1.s;
            s1a += v0; s2a += v0 * v0;
            s1b += v1; s2b += v1 * v1;
        }
    }

    s1a += __shfl_down(s1a, 32); s1a += __shfl_down(s1a, 16);
    s2a += __shfl_down(s2a, 32); s2a += __shfl_down(s2a, 16);
    s1b += __shfl_down(s1b, 32); s1b += __shfl_down(s1b, 16);
    s2b += __shfl_down(s2b, 32); s2b += __shfl_down(s2b, 16);
    if (qd == 0) {
        atomicAdd(&gstats[n0], s1a);
        atomicAdd(&gstats[FEAT + n0], s2a);
        atomicAdd(&gstats[n1], s1b);
        atomicAdd(&gstats[FEAT + n1], s2b);
    }
}

// ---- bn: f16 x -> BN+LeakyReLU -> f32 out --------------------------------------
__global__ __launch_bounds__(256) void enc_bn_h(
    const unsigned short* __restrict__ xh, float* __restrict__ out,
    const float* __restrict__ gstats,
    const float* __restrict__ gamma, const float* __restrict__ beta)
{
    __shared__ float sScale[FEAT], sShift[FEAT];
    const int t = threadIdx.x;
    if (t < FEAT) {
        float s1 = gstats[t], s2 = gstats[FEAT + t];
        float mean = s1 * (1.0f / NB);
        float var = s2 * (1.0f / NB) - mean * mean;
        float sc = gamma[t] * rsqrtf(var + 1e-5f);
        sScale[t] = sc;
        sShift[t] = beta[t] - mean * sc;
    }
    __syncthreads();
    const int f8 = (t & 15) * 8;   // thread-invariant feature octet
    const float4 sc0 = *(const float4*)&sScale[f8], sc1 = *(const float4*)&sScale[f8 + 4];
    const float4 sh0 = *(const float4*)&sShift[f8], sh1 = *(const float4*)&sShift[f8 + 4];

    const uint4* x4 = (const uint4*)xh;
    float4* o4 = (float4*)out;
    const int total8 = NB * FEAT / 8;   // 800k
    for (int e = blockIdx.x * 256 + t; e < total8; e += gridDim.x * 256) {
        uint4 v = x4[e];
        union { unsigned u; __half2 h; } w;
        float4 r0, r1; float2 f; float y;
        w.u = v.x; f = __half22float2(w.h);
        y = f.x * sc0.x + sh0.x; r0.x = (y >= 0.f) ? y : 0.01f * y;
        y = f.y * sc0.y + sh0.y; r0.y = (y >= 0.f) ? y : 0.01f * y;
        w.u = v.y; f = __half22float2(w.h);
        y = f.x * sc0.z + sh0.z; r0.z = (y >= 0.f) ? y : 0.01f * y;
        y = f.y * sc0.w + sh0.w; r0.w = (y >= 0.f) ? y : 0.01f * y;
        w.u = v.z; f = __half22float2(w.h);
        y = f.x * sc1.x + sh1.x; r1.x = (y >= 0.f) ? y : 0.01f * y;
        y = f.y * sc1.y + sh1.y; r1.y = (y >= 0.f) ? y : 0.01f * y;
        w.u = v.w; f = __half22float2(w.h);
        y = f.x * sc1.z + sh1.z; r1.z = (y >= 0.f) ? y : 0.01f * y;
        y = f.y * sc1.w + sh1.w; r1.w = (y >= 0.f) ? y : 0.01f * y;
        o4[e * 2] = r0; o4[e * 2 + 1] = r1;
    }
}

// ======================= fallback (f32 path, R1-proven) =========================
#define WT_LD 136
#define A_LD  136
__global__ __launch_bounds__(256, 4) void enc_gemm_f(
    const float* __restrict__ raw, const float* __restrict__ W,
    const int* __restrict__ idx, float* __restrict__ out,
    float* __restrict__ gstats)
{
    __shared__ unsigned short sWt[128 * WT_LD];
    __shared__ unsigned short sA2[16 * A_LD];
    __shared__ int sidx[256];
    const int t = threadIdx.x;
    #pragma unroll 4
    for (int i = 0; i < 64; ++i) {
        int e = t + i * 256;
        int f = e >> 7, n = e & 127;
        sWt[n * WT_LD + f] = f2bf(W[e]);
    }
    const int lane = t & 63, wv = t >> 6, ln = lane & 15, qd = lane >> 4;
    const int c = t & 31, g = t >> 5;
    const int n0 = wv * 32 + ln, n1 = n0 + 16;
    float s1a = 0.f, s2a = 0.f, s1b = 0.f, s2b = 0.f;
    const float4* raw4 = (const float4*)raw;
    for (int tile = blockIdx.x; tile < NTILES; tile += gridDim.x) {
        const int i0 = tile * 16;
        __syncthreads();
        sidx[t] = idx[i0 * KNEI + t];
        __syncthreads();
        #pragma unroll
        for (int rr = 0; rr < 2; ++rr) {
            const int r = g * 2 + rr;
            const int* ip = &sidx[r * KNEI];
            float4 acc = {0.f, 0.f, 0.f, 0.f};
            #pragma unroll
            for (int k = 0; k < KNEI; ++k) {
                float4 v = raw4[(size_t)ip[k] * 32 + c];
                acc.x += v.x; acc.y += v.y; acc.z += v.z; acc.w += v.w;
            }
            ushort4 b;
            b.x = f2bf(acc.x * 0.0625f); b.y = f2bf(acc.y * 0.0625f);
            b.z = f2bf(acc.z * 0.0625f); b.w = f2bf(acc.w * 0.0625f);
            *(ushort4*)&sA2[r * A_LD + c * 4] = b;
        }
        __syncthreads();
        f32x4 acc0 = {0.f, 0.f, 0.f, 0.f}, acc1 = {0.f, 0.f, 0.f, 0.f};
        #pragma unroll
        for (int kt = 0; kt < 4; ++kt) {
            const int k0 = kt * 32 + qd * 8;
            bf16x8 aa  = *(const bf16x8*)&sA2[ln * A_LD + k0];
            bf16x8 bb0 = *(const bf16x8*)&sWt[n0 * WT_LD + k0];
            bf16x8 bb1 = *(const bf16x8*)&sWt[n1 * WT_LD + k0];
            acc0 = __builtin_amdgcn_mfma_f32_16x16x32_bf16(aa, bb0, acc0, 0, 0, 0);
            acc1 = __builtin_amdgcn_mfma_f32_16x16x32_bf16(aa, bb1, acc1, 0, 0, 0);
        }
        #pragma unroll
        for (int ri = 0; ri < 4; ++ri) {
            const int row = i0 + qd * 4 + ri;
            float v0 = acc0[ri], v1 = acc1[ri];
            out[row * FEAT + n0] = v0;
            out[row * FEAT + n1] = v1;
            s1a += v0; s2a += v0 * v0;
            s1b += v1; s2b += v1 * v1;
        }
    }
    s1a += __shfl_down(s1a, 32); s1a += __shfl_down(s1a, 16);
    s2a += __shfl_down(s2a, 32); s2a += __shfl_down(s2a, 16);
    s1b += __shfl_down(s1b, 32); s1b += __shfl_down(s1b, 16);
    s2b += __shfl_down(s2b, 32); s2b += __shfl_down(s2b, 16);
    if (qd == 0) {
        atomicAdd(&gstats[n0], s1a);
        atomicAdd(&gstats[FEAT + n0], s2a);
        atomicAdd(&gstats[n1], s1b);
        atomicAdd(&gstats[FEAT + n1], s2b);
    }
}

__global__ __launch_bounds__(256) void enc_bn_f(
    float* __restrict__ out, const float* __restrict__ gstats,
    const float* __restrict__ gamma, const float* __restrict__ beta)
{
    __shared__ float sScale[FEAT], sShift[FEAT];
    const int t = threadIdx.x;
    if (t < FEAT) {
        float s1 = gstats[t], s2 = gstats[FEAT + t];
        float mean = s1 * (1.0f / NB);
        float var = s2 * (1.0f / NB) - mean * mean;
        float sc = gamma[t] * rsqrtf(var + 1e-5f);
        sScale[t] = sc;
        sShift[t] = beta[t] - mean * sc;
    }
    __syncthreads();
    const int f4 = (t & 31) * 4;
    const float4 sc = *(const float4*)&sScale[f4];
    const float4 sh = *(const float4*)&sShift[f4];
    const int total4 = NB * FEAT / 4;
    float4* o4 = (float4*)out;
    for (int e = blockIdx.x * 256 + t; e < total4; e += gridDim.x * 256) {
        float4 v = o4[e];
        float4 r; float y;
        y = v.x * sc.x + sh.x; r.x = (y >= 0.f) ? y : 0.01f * y;
        y = v.y * sc.y + sh.y; r.y = (y >= 0.f) ? y : 0.01f * y;
        y = v.z * sc.z + sh.z; r.z = (y >= 0.f) ? y : 0.01f * y;
        y = v.w * sc.w + sh.w; r.w = (y >= 0.f) ? y : 0.01f * y;
        o4[e] = r;
    }
}

extern "C" void kernel_launch(void* const* d_in, const int* in_sizes, int n_in,
                              void* d_out, int out_size, void* d_ws, size_t ws_size,
                              hipStream_t stream) {
    const float* raw   = (const float*)d_in[0];
    const float* W     = (const float*)d_in[1];
    const float* gamma = (const float*)d_in[2];
    const float* beta  = (const float*)d_in[3];
    const int*   idx   = (const int*)d_in[4];
    float* out = (float*)d_out;

    char* ws = (char*)d_ws;
    float* gstats = (float*)(ws + OFF_STATS);

    if (ws_size >= WS_NEEDED) {
        int* qcnt            = (int*)(ws + OFF_QCNT);
        unsigned short* Wt   = (unsigned short*)(ws + OFF_WT);
        unsigned short* rawp = (unsigned short*)(ws + OFF_RAWP);
        unsigned short* nf   = (unsigned short*)(ws + OFF_NF);
        unsigned short* xh   = (unsigned short*)(ws + OFF_XH);
        enc_conv<<<2048, 256, 0, stream>>>(raw, W, rawp, Wt, gstats, qcnt);
        enc_gather_p<<<2048, 256, 0, stream>>>(rawp, idx, nf, qcnt);
        enc_mm<<<782, 256, 0, stream>>>(nf, Wt, xh, gstats);
        enc_bn_h<<<1024, 256, 0, stream>>>(xh, out, gstats, gamma, beta);
    } else {
        hipMemsetAsync(gstats, 0, 2 * FEAT * sizeof(float), stream);
        enc_gemm_f<<<1024, 256, 0, stream>>>(raw, W, idx, out, gstats);
        enc_bn_f<<<1024, 256, 0, stream>>>(out, gstats, gamma, beta);
    }
}